// Round 8
// baseline (291.776 us; speedup 1.0000x reference)
//
#include <hip/hip_runtime.h>
#include <cmath>

// ---------------------------------------------------------------------------
// WireframeDetector: NMS -> top-k 300 junctions -> line sampling (bilinear +
// maxpool) -> 3-layer MLP (fp16 MFMA for the two 1024-wide GEMMs).
// R23: amortize the fixed ~1300 cyc/round overhead (barrier + post-barrier
//      lgkm latency; nothing hides it at 1 wave/SIMD -- register audit shows
//      acc[5][8]=160 regs/thread caps this family at 1 block/CU) by HALVING
//      round count: BK=64 compute-rounds (16), each stages 2 BK=32 chunks
//      (52 KiB), one barrier + one counted vmcnt(13)/wave, 80 MFMAs/wave.
//      Ring-3 x 52 KiB = 156 KiB LDS (fits: 1 block/CU by design).
//      Delivery measured ~29 GB/s/CU across R18/R21/R22 configs independent
//      of occupancy -> the round critical path, not bandwidth, is the wall.
//      Swizzled A/B layouts, producers, epilogues, grid identical to R22.
// ---------------------------------------------------------------------------

typedef _Float16 f16;
typedef _Float16 f16x2 __attribute__((ext_vector_type(2)));
typedef _Float16 f16x8 __attribute__((ext_vector_type(8)));
typedef float f32x4 __attribute__((ext_vector_type(4)));

#define HWD 128
#define NPIX 16384            // 128*128
#define TOPK_N 300
#define NLINES 20000
#define MPAD 20160            // 126 * 160 (padded line count)
#define KDIM 1024
#define NDIM 1024
#define MAXCAND 4096

// A operand layout (feats, h1), f16 elems:
//   idx(row,k) = ((k>>5)*MPAD + row)*32 + slot(row,k)*8 + (k&7)
//   slot(row,k) = ((k>>3)&3) ^ ((row>>1)&3)       (XOR bank swizzle)
// B operand layout (W1T, W2T): same with row->n, MPAD->1024:
//   idx(n,k)   = ((k>>5)*1024 + n)*32 + slot(n,k)*8 + (k&7)
// Each 32-k chunk is contiguous (A: 10 KiB per 160 rows, B: 16 KiB per 256
// rows) and IS the LDS image. Fragment ds_read_b128 offset is lane-constant:
// swz = (quad ^ ((col16>>1)&3))*8.

// async global->LDS, 16B per lane; LDS dest = wave-uniform base + lane*16
#define G2L(gp, lp) __builtin_amdgcn_global_load_lds( \
    (const __attribute__((address_space(1))) void*)(gp), \
    (__attribute__((address_space(3))) void*)(lp), 16, 0, 0)

// ---------------------------------------------------------------------------
// Fused preprocessing, one dispatch of 764 blocks:
//   blocks 0..127   : transpose loi [C][H][W] fp32 -> loiT [H][W][C] fp16
//   blocks 128..639 : W1/W2 [K][N] fp32 -> swizzled K-chunk-tiled fp16
//   blocks 640..703 : 3x3 NMS on jloc, survivors -> cand list
//   blocks 704..763 : zero out[60000] (consumed by gemm2's atomicAdd epilogue)
// ---------------------------------------------------------------------------
__global__ __launch_bounds__(256) void preproc_kernel(
    const float* __restrict__ loi, f16* __restrict__ loiT,
    const float* __restrict__ W1, f16* __restrict__ W1T,
    const float* __restrict__ W2, f16* __restrict__ W2T,
    const float* __restrict__ jloc, unsigned long long* __restrict__ cand,
    int* __restrict__ count, float* __restrict__ out, int out_n)
{
    const int bid = blockIdx.x;
    const int tid = threadIdx.x;
    if (bid < 128) {
        __shared__ f16 t[128 * 130];     // [x][c], +2 pad kills bank conflicts
        const int y = bid;
        #pragma unroll 4
        for (int it = 0; it < 64; ++it) {
            int idx = it * 256 + tid;    // c-major, x fast -> coalesced read
            int c = idx >> 7, x = idx & 127;
            t[x * 130 + c] = (f16)loi[c * NPIX + y * HWD + x];
        }
        __syncthreads();
        #pragma unroll
        for (int it = 0; it < 8; ++it) {
            int j = it * 256 + tid;      // 2048 chunks of 8 f16
            int x = j >> 4, cc = (j & 15) * 8;
            f16x8 v;
            #pragma unroll
            for (int u = 0; u < 8; ++u) v[u] = t[x * 130 + cc + u];
            *(f16x8*)(loiT + (y * HWD + x) * HWD + cc) = v;
        }
    } else if (bid < 640) {
        const int b = bid - 128;         // 0..511
        const float* W = (b < 256) ? W1 : W2;
        f16* Wt = (b < 256) ? W1T : W2T;
        const int bb = b & 255;
        __shared__ f16 t[64 * 66];
        const int k0 = (bb >> 4) * 64;
        const int n0 = (bb & 15) * 64;
        #pragma unroll 4
        for (int it = 0; it < 16; ++it) {
            int i = it * 256 + tid;      // coalesced read over n
            int r = i >> 6, c = i & 63;
            t[c * 66 + r] = (f16)W[(size_t)(k0 + r) * NDIM + n0 + c];
        }
        __syncthreads();
        #pragma unroll
        for (int it = 0; it < 2; ++it) {
            int j = it * 256 + tid;
            int nr = j >> 3, kc = (j & 7) * 8;
            f16x8 v;
            #pragma unroll
            for (int u = 0; u < 8; ++u) v[u] = t[nr * 66 + kc + u];
            const int kk = k0 + kc;      // multiple of 8
            const int n = n0 + nr;
            const int slot = ((kk >> 3) & 3) ^ ((n >> 1) & 3);
            *(f16x8*)(Wt + ((size_t)(kk >> 5) * NDIM + n) * 32 + slot * 8) = v;
        }
    } else if (bid < 704) {
        const int p = (bid - 640) * 256 + tid;   // 64 blocks x 256 = 16384
        const int y = p >> 7, x = p & 127;
        const float c = jloc[p];
        float m = c;
        for (int dy = -1; dy <= 1; ++dy) {
            int yy = y + dy;
            if (yy < 0 || yy >= HWD) continue;
            for (int dx = -1; dx <= 1; ++dx) {
                int xx = x + dx;
                if (xx < 0 || xx >= HWD) continue;
                m = fmaxf(m, jloc[yy * HWD + xx]);
            }
        }
        if (c == m && c > 0.0f) {
            int pos = atomicAdd(count, 1);
            if (pos < MAXCAND) {
                unsigned int ub = __float_as_uint(c);
                cand[pos] = ((unsigned long long)ub << 32) |
                            (unsigned long long)(0xFFFFFFFFu - (unsigned int)p);
            }
        }
    } else {
        const int base = (bid - 704) * 1024 + tid * 4;   // 60 blocks cover 61440
        #pragma unroll
        for (int u = 0; u < 4; ++u)
            if (base + u < out_n) out[base + u] = 0.f;
    }
}

// ---------------------------------------------------------------------------
// Rank-select top-300, LDS-cached. Keys unique => ranks exact; matches
// jax.lax.top_k order (value desc, index asc).
// ---------------------------------------------------------------------------
__global__ __launch_bounds__(256) void rank_junc_kernel(
    const unsigned long long* __restrict__ cand, const int* __restrict__ count,
    const float* __restrict__ joff, float* __restrict__ juncs /* [300][2] */)
{
    __shared__ unsigned long long keys[MAXCAND];   // 32 KB
    const int n = min(*count, MAXCAND);
    const int t = blockIdx.x * 256 + threadIdx.x;  // 16 blocks = 4096 threads
    for (int i = threadIdx.x; i < n; i += 256)
        keys[i] = cand[i];
    __syncthreads();
    if (t >= n) return;
    const unsigned long long key = keys[t];
    int rank = 0;
    int j = 0;
    for (; j + 4 <= n; j += 4) {
        rank += (keys[j]     > key);
        rank += (keys[j + 1] > key);
        rank += (keys[j + 2] > key);
        rank += (keys[j + 3] > key);
    }
    for (; j < n; ++j) rank += (keys[j] > key);
    if (rank < TOPK_N) {
        unsigned int p = 0xFFFFFFFFu - (unsigned int)(key & 0xFFFFFFFFull);
        // x = idx%w + (sigmoid(joff0)-0.5) + 0.5 = idx%w + sigmoid(joff0)
        float sx = 1.0f / (1.0f + expf(-joff[p]));
        float sy = 1.0f / (1.0f + expf(-joff[NPIX + p]));
        juncs[2 * rank + 0] = (float)(p & 127) + sx;
        juncs[2 * rank + 1] = (float)(p >> 7) + sy;
    }
}

// ---------------------------------------------------------------------------
// Per-line sampling, deduplicated: lanes 0..31 compute the 4 tap offsets +
// weights of the 32 points once into LDS; channel loop (64 lanes, 2 ch each)
// reads them as wave-uniform broadcasts. 4 lines/block (wave per line).
// Output feats in the XOR-swizzled A operand layout.
// ---------------------------------------------------------------------------
__global__ __launch_bounds__(256) void sample_kernel(
    const f16* __restrict__ loiT, const float* __restrict__ juncs,
    const int* __restrict__ edge_idx, f16* __restrict__ feats)
{
    const int wv = threadIdx.x >> 6;
    const int l = blockIdx.x * 4 + wv;
    const int lane = threadIdx.x & 63;

    __shared__ int   soff[4][32][4];   // channel-base element offsets
    __shared__ float swt[4][32][4];    // bilinear weights

    if (lane < 32) {
        const int e0 = edge_idx[2 * l], e1 = edge_idx[2 * l + 1];
        const float ux = juncs[2 * e0], uy = juncs[2 * e0 + 1];
        const float vx = juncs[2 * e1], vy = juncs[2 * e1 + 1];
        const int j = lane;
        const float t = (float)j * (1.0f / 31.0f);
        const float px = ux * t + vx * (1.0f - t) - 0.5f;
        const float py = uy * t + vy * (1.0f - t) - 0.5f;
        float fx0 = fminf(fmaxf(floorf(px), 0.0f), 127.0f);
        float fy0 = fminf(fmaxf(floorf(py), 0.0f), 127.0f);
        float fx1 = fminf(fx0 + 1.0f, 127.0f);
        float fy1 = fminf(fy0 + 1.0f, 127.0f);
        int ix0 = (int)fx0, iy0 = (int)fy0, ix1 = (int)fx1, iy1 = (int)fy1;
        soff[wv][j][0] = (iy0 * HWD + ix0) * HWD;
        soff[wv][j][1] = (iy1 * HWD + ix0) * HWD;
        soff[wv][j][2] = (iy0 * HWD + ix1) * HWD;
        soff[wv][j][3] = (iy1 * HWD + ix1) * HWD;
        swt[wv][j][0] = (fy1 - py) * (fx1 - px);
        swt[wv][j][1] = (py - fy0) * (fx1 - px);
        swt[wv][j][2] = (fy1 - py) * (px - fx0);
        swt[wv][j][3] = (py - fy0) * (px - fx0);
    }
    __syncthreads();

    const int c2 = lane * 2;
    f16x8 o0, o1;
    #pragma unroll
    for (int p = 0; p < 8; ++p) {
        float m0 = -INFINITY, m1 = -INFINITY;
        #pragma unroll
        for (int jj = 0; jj < 4; ++jj) {
            const int j = p * 4 + jj;
            const int b00 = soff[wv][j][0], b10 = soff[wv][j][1];
            const int b01 = soff[wv][j][2], b11 = soff[wv][j][3];
            const float w00 = swt[wv][j][0], w10 = swt[wv][j][1];
            const float w01 = swt[wv][j][2], w11 = swt[wv][j][3];
            f16x2 v00 = *(const f16x2*)(loiT + b00 + c2);
            f16x2 v10 = *(const f16x2*)(loiT + b10 + c2);
            f16x2 v01 = *(const f16x2*)(loiT + b01 + c2);
            f16x2 v11 = *(const f16x2*)(loiT + b11 + c2);
            float s0 = (float)v00.x * w00 + (float)v10.x * w10 +
                       (float)v01.x * w01 + (float)v11.x * w11;
            float s1 = (float)v00.y * w00 + (float)v10.y * w10 +
                       (float)v01.y * w01 + (float)v11.y * w11;
            m0 = fmaxf(m0, s0);
            m1 = fmaxf(m1, s1);
        }
        o0[p] = (f16)m0;   // feature k = 16*lane + p
        o1[p] = (f16)m1;   // feature k = 16*lane + 8 + p
    }
    // A layout: chunk = lane>>1; o0 oct = 2*(lane&1), o1 oct = 2*(lane&1)+1;
    // slot = oct ^ ((l>>1)&3).
    const int rs = (l >> 1) & 3;
    const int oct0 = (lane & 1) * 2;
    f16* base = feats + ((size_t)(lane >> 1) * MPAD + l) * 32;
    *(f16x8*)(base + ((oct0 ^ rs) * 8)) = o0;
    *(f16x8*)(base + (((oct0 + 1) ^ rs) * 8)) = o1;
}

// ---------------------------------------------------------------------------
// GEMM: 160x256 tile, 256 threads, 2x2 waves (each 80 rows x 128 cols,
// acc[5][8]). 16 rounds of BK=64 (two BK=32 chunks per round). Ring of 3
// round-buffers (52 KiB each: A0 A1 B0 B1 = 10+10+16+16 KiB), prefetch
// distance 2 rounds. Per round:
//   s_waitcnt vmcnt(13)   <- per-wave counted (every wave issues 13 G2L per
//                            round: 5 A segs {w+4i} + 8 B segs {8w..8w+7});
//                            forces THIS round's buffer (staged 2 rounds
//                            ago); next round's 13 stay in flight. Last
//                            round drains vmcnt(0).
//   s_barrier             <- all waves' segs of this buffer now complete;
//                            also proves reads of buf (r+2)%3 finished
//   STAGE(r+2)            <- 13 G2L into buffer (r+2)%3
//   chunk0: ds_read af[5]/bf[8] (XOR-swizzled) + 40 MFMA
//   chunk1: same at A+5120 / B+8192
// One barrier + one wait per 80 MFMAs (was per 40) -> fixed round overhead
// (~1300 cyc: barrier + post-barrier lgkm latency) amortized 2x.
// LDS 156 KiB -> 1 block/CU (register file caps this family there anyway).
// head=0: C = relu(A@Bt^T + bias), stored in swizzled A layout fp16.
// head=1: v = relu(A@Bt^T + bias); out[m][j] += v . W3  (atomicAdd, + b3 once)
// ---------------------------------------------------------------------------
__global__ __launch_bounds__(256, 1) void gemm_bias_relu_kernel(
    const f16* __restrict__ A, const f16* __restrict__ Bt,
    const float* __restrict__ bias, f16* __restrict__ C,
    const float* __restrict__ W3, const float* __restrict__ b3,
    float* __restrict__ out, int K, int head)
{
    extern __shared__ f16 lds[];                 // 3 * 26624 f16 = 156 KiB
    const int tid = threadIdx.x;
    const int wave = tid >> 6, lane = tid & 63;
    const int wm = wave >> 1, wn = wave & 1;
    const int m0 = blockIdx.y * 160;             // y = mblk (slow)
    const int n0 = blockIdx.x * 256;             // x = nblk (fast)

    const int col16 = lane & 15;
    const int quad = lane >> 4;
    const int swz = (quad ^ ((col16 >> 1) & 3)) * 8;   // lane-const slot offset

    f32x4 acc[5][8];
    #pragma unroll
    for (int mi = 0; mi < 5; ++mi)
        #pragma unroll
        for (int ni = 0; ni < 8; ++ni)
            acc[mi][ni] = (f32x4){0.f, 0.f, 0.f, 0.f};

    const size_t strideA = (size_t)MPAD * 32;    // f16 per k-chunk
    const size_t strideB = (size_t)NDIM * 32;
    const f16* gA = A + (size_t)m0 * 32 + lane * 8;
    const f16* gB = Bt + (size_t)n0 * 32 + lane * 8;

    // Round buffer image (f16 elems): [A0:0..5119][A1:5120..10239]
    // [B0:10240..18431][B1:18432..26623]. A segs s=0..19 at s*512 (chunk
    // s>=10, row-off (s%10)*512); B segs sB=0..31 at 10240+sB*512 (chunk
    // sB>=16, i.e. wave>=2, n-off (sB%16)*512). All branches wave-uniform.
#define STAGE(R) do { \
        f16* lb_ = lds + ((R) % 3) * 26624; \
        const f16* gar_ = gA + (size_t)(2 * (R)) * strideA; \
        _Pragma("unroll") \
        for (int i_ = 0; i_ < 5; ++i_) { \
            const int s_ = wave + 4 * i_; \
            const f16* g_ = gar_ + (s_ >= 10 ? strideA : 0) + (s_ % 10) * 512; \
            G2L(g_, lb_ + s_ * 512); \
        } \
        const f16* gbr_ = gB + (size_t)(2 * (R)) * strideB \
                          + (wave >= 2 ? strideB : 0); \
        const int sb0_ = 8 * wave; \
        _Pragma("unroll") \
        for (int j_ = 0; j_ < 8; ++j_) { \
            const int sB_ = sb0_ + j_; \
            G2L(gbr_ + (sB_ & 15) * 512, lb_ + 10240 + sB_ * 512); \
        } \
    } while (0)

    // Prologue: order pinned so each wave's oldest 13 G2L are STAGE(0).
    STAGE(0);
    asm volatile("" ::: "memory");
    STAGE(1);
    asm volatile("" ::: "memory");

    const int NR = K >> 6;                       // 16 rounds
    for (int r = 0; r < NR; ++r) {
        if (r + 1 < NR)
            asm volatile("s_waitcnt vmcnt(13)" ::: "memory");
        else
            asm volatile("s_waitcnt vmcnt(0)" ::: "memory");
        __builtin_amdgcn_s_barrier();
        if (r + 2 < NR) STAGE(r + 2);
        asm volatile("" ::: "memory");

        const f16* buf = lds + (r % 3) * 26624;
        {   // chunk 0 (k-chunk 2r)
            const f16* pA = buf + (wm * 80 + col16) * 32 + swz;
            const f16* pB = buf + 10240 + (wn * 128 + col16) * 32 + swz;
            f16x8 af[5], bf[8];
            #pragma unroll
            for (int i = 0; i < 5; ++i)
                af[i] = *(const f16x8*)(pA + i * 512);
            #pragma unroll
            for (int i = 0; i < 8; ++i)
                bf[i] = *(const f16x8*)(pB + i * 512);
            #pragma unroll
            for (int mi = 0; mi < 5; ++mi)
                #pragma unroll
                for (int ni = 0; ni < 8; ++ni)
                    acc[mi][ni] = __builtin_amdgcn_mfma_f32_16x16x32_f16(
                        af[mi], bf[ni], acc[mi][ni], 0, 0, 0);
        }
        {   // chunk 1 (k-chunk 2r+1)
            const f16* pA = buf + 5120 + (wm * 80 + col16) * 32 + swz;
            const f16* pB = buf + 18432 + (wn * 128 + col16) * 32 + swz;
            f16x8 af[5], bf[8];
            #pragma unroll
            for (int i = 0; i < 5; ++i)
                af[i] = *(const f16x8*)(pA + i * 512);
            #pragma unroll
            for (int i = 0; i < 8; ++i)
                bf[i] = *(const f16x8*)(pB + i * 512);
            #pragma unroll
            for (int mi = 0; mi < 5; ++mi)
                #pragma unroll
                for (int ni = 0; ni < 8; ++ni)
                    acc[mi][ni] = __builtin_amdgcn_mfma_f32_16x16x32_f16(
                        af[mi], bf[ni], acc[mi][ni], 0, 0, 0);
        }
    }
#undef STAGE

    if (!head) {
        #pragma unroll
        for (int ni = 0; ni < 8; ++ni) {
            const int n = n0 + wn * 128 + ni * 16 + col16;
            const float b = bias[n];
            const size_t rb = (size_t)(n >> 5) * MPAD;
            const int noct = (n >> 3) & 3, ne = n & 7;
            #pragma unroll
            for (int mi = 0; mi < 5; ++mi) {
                #pragma unroll
                for (int r = 0; r < 4; ++r) {
                    const int m = m0 + wm * 80 + mi * 16 + quad * 4 + r;
                    float v = fmaxf(acc[mi][ni][r] + b, 0.f);
                    C[(rb + m) * 32 + ((noct ^ ((m >> 1) & 3)) * 8) + ne] = (f16)v;
                }
            }
        }
    } else {
        float bb[8], w3c[8][3];
        #pragma unroll
        for (int ni = 0; ni < 8; ++ni) {
            const int n = n0 + wn * 128 + ni * 16 + col16;
            bb[ni] = bias[n];
            #pragma unroll
            for (int jj = 0; jj < 3; ++jj) w3c[ni][jj] = W3[n * 3 + jj];
        }
        const bool addb3 = (blockIdx.x == 0 && wn == 0);
        #pragma unroll
        for (int mi = 0; mi < 5; ++mi) {
            #pragma unroll
            for (int r = 0; r < 4; ++r) {
                float s0 = 0.f, s1 = 0.f, s2 = 0.f;
                #pragma unroll
                for (int ni = 0; ni < 8; ++ni) {
                    float v = fmaxf(acc[mi][ni][r] + bb[ni], 0.f);
                    s0 += v * w3c[ni][0];
                    s1 += v * w3c[ni][1];
                    s2 += v * w3c[ni][2];
                }
                #pragma unroll
                for (int mask = 1; mask <= 8; mask <<= 1) {
                    s0 += __shfl_xor(s0, mask);
                    s1 += __shfl_xor(s1, mask);
                    s2 += __shfl_xor(s2, mask);
                }
                if (col16 == 0) {
                    const int m = m0 + wm * 80 + mi * 16 + quad * 4 + r;
                    if (m < NLINES) {
                        atomicAdd(&out[m * 3 + 0], s0 + (addb3 ? b3[0] : 0.f));
                        atomicAdd(&out[m * 3 + 1], s1 + (addb3 ? b3[1] : 0.f));
                        atomicAdd(&out[m * 3 + 2], s2 + (addb3 ? b3[2] : 0.f));
                    }
                }
            }
        }
    }
}

// ---------------------------------------------------------------------------
extern "C" void kernel_launch(void* const* d_in, const int* in_sizes, int n_in,
                              void* d_out, int out_size, void* d_ws, size_t ws_size,
                              hipStream_t stream)
{
    const float* jloc = (const float*)d_in[0];
    const float* joff = (const float*)d_in[1];
    const float* loi  = (const float*)d_in[2];
    const int*   eidx = (const int*)d_in[3];
    const float* W1   = (const float*)d_in[4];
    const float* b1   = (const float*)d_in[5];
    const float* W2   = (const float*)d_in[6];
    const float* b2   = (const float*)d_in[7];
    const float* W3   = (const float*)d_in[8];
    const float* b3   = (const float*)d_in[9];
    float* out = (float*)d_out;

    char* ws = (char*)d_ws;
    f16*   loiT  = (f16*)(ws);                            // 4 MB
    f16*   W1T   = (f16*)(ws + ((size_t)4 << 20));        // 2 MB
    f16*   W2T   = (f16*)(ws + ((size_t)6 << 20));        // 2 MB
    float* juncs = (float*)(ws + ((size_t)8 << 20));      // 2.4 KB
    int*   count = (int*)(ws + ((size_t)8 << 20) + 4096);
    unsigned long long* cand =
        (unsigned long long*)(ws + ((size_t)8 << 20) + 8192);  // 32 KB
    f16*   feats = (f16*)(ws + ((size_t)9 << 20));        // 41.3 MB (tiled MPADx1024)
    f16*   h1    = (f16*)(ws + ((size_t)52 << 20));       // 41.3 MB (tiled)

    static int attr_done = 0;
    if (!attr_done) {
        (void)hipFuncSetAttribute(
            reinterpret_cast<const void*>(&gemm_bias_relu_kernel),
            hipFuncAttributeMaxDynamicSharedMemorySize, 159744);
        attr_done = 1;
    }

    hipMemsetAsync(count, 0, sizeof(int), stream);
    preproc_kernel<<<dim3(764), dim3(256), 0, stream>>>(
        loi, loiT, W1, W1T, W2, W2T, jloc, cand, count, out, out_size);
    rank_junc_kernel<<<dim3(MAXCAND / 256), dim3(256), 0, stream>>>(
        cand, count, joff, juncs);
    sample_kernel<<<dim3(NLINES / 4), dim3(256), 0, stream>>>(loiT, juncs, eidx, feats);
    gemm_bias_relu_kernel<<<dim3(NDIM / 256, MPAD / 160), dim3(256), 159744, stream>>>(
        feats, W1T, b1, h1, nullptr, nullptr, nullptr, KDIM, 0);
    gemm_bias_relu_kernel<<<dim3(NDIM / 256, MPAD / 160), dim3(256), 159744, stream>>>(
        h1, W2T, b2, nullptr, W3, b3, out, KDIM, 1);
}

// Round 9
// 275.795 us; speedup vs baseline: 1.0579x; 1.0579x over previous
//
#include <hip/hip_runtime.h>
#include <cmath>

// ---------------------------------------------------------------------------
// WireframeDetector: NMS -> top-k 300 junctions -> line sampling (bilinear +
// maxpool) -> 3-layer MLP (fp16 MFMA for the two 1024-wide GEMMs).
// R24: revert GEMM to R22 (best measured: 61 us/GEMM; R23's BK=64 ring
//      forced 1 block/CU + 208 VGPR -> 78.7 us, reverted) and add an
//      XCD-chunked tile mapping: 1D grid 504 = 63 x 8 XCDs; consecutive
//      block ids round-robin across XCDs, so tile = (id&7)*63 + (id>>3),
//      mblk-major within each XCD -> an A-panel's 4 consumer tiles all run
//      in ONE XCD (1 HBM fetch + 3 local-L2 hits, was 4 cross-XCD fetches
//      absorbed by L3). Model: GEMM ~= staged 420 MB / 6.9 TB/s G2L
//      delivery; (160,256) ring-3 is the largest tile fitting the 80 KiB
//      2-block LDS budget -> family wall.
// ---------------------------------------------------------------------------

typedef _Float16 f16;
typedef _Float16 f16x2 __attribute__((ext_vector_type(2)));
typedef _Float16 f16x8 __attribute__((ext_vector_type(8)));
typedef float f32x4 __attribute__((ext_vector_type(4)));

#define HWD 128
#define NPIX 16384            // 128*128
#define TOPK_N 300
#define NLINES 20000
#define MPAD 20160            // 126 * 160 (padded line count)
#define KDIM 1024
#define NDIM 1024
#define MAXCAND 4096

// A operand layout (feats, h1), f16 elems:
//   idx(row,k) = ((k>>5)*MPAD + row)*32 + slot(row,k)*8 + (k&7)
//   slot(row,k) = ((k>>3)&3) ^ ((row>>1)&3)       (XOR bank swizzle)
// B operand layout (W1T, W2T): same with row->n, MPAD->1024:
//   idx(n,k)   = ((k>>5)*1024 + n)*32 + slot(n,k)*8 + (k&7)
// Each 32-k chunk is contiguous (A: 10 KiB per 160 rows, B: 16 KiB per 256
// rows) and IS the LDS image. Fragment ds_read_b128 offset is lane-constant:
// swz = (quad ^ ((col16>>1)&3))*8.

// async global->LDS, 16B per lane; LDS dest = wave-uniform base + lane*16
#define G2L(gp, lp) __builtin_amdgcn_global_load_lds( \
    (const __attribute__((address_space(1))) void*)(gp), \
    (__attribute__((address_space(3))) void*)(lp), 16, 0, 0)

// ---------------------------------------------------------------------------
// Fused preprocessing, one dispatch of 764 blocks:
//   blocks 0..127   : transpose loi [C][H][W] fp32 -> loiT [H][W][C] fp16
//   blocks 128..639 : W1/W2 [K][N] fp32 -> swizzled K-chunk-tiled fp16
//   blocks 640..703 : 3x3 NMS on jloc, survivors -> cand list
//   blocks 704..763 : zero out[60000] (consumed by gemm2's atomicAdd epilogue)
// ---------------------------------------------------------------------------
__global__ __launch_bounds__(256) void preproc_kernel(
    const float* __restrict__ loi, f16* __restrict__ loiT,
    const float* __restrict__ W1, f16* __restrict__ W1T,
    const float* __restrict__ W2, f16* __restrict__ W2T,
    const float* __restrict__ jloc, unsigned long long* __restrict__ cand,
    int* __restrict__ count, float* __restrict__ out, int out_n)
{
    const int bid = blockIdx.x;
    const int tid = threadIdx.x;
    if (bid < 128) {
        __shared__ f16 t[128 * 130];     // [x][c], +2 pad kills bank conflicts
        const int y = bid;
        #pragma unroll 4
        for (int it = 0; it < 64; ++it) {
            int idx = it * 256 + tid;    // c-major, x fast -> coalesced read
            int c = idx >> 7, x = idx & 127;
            t[x * 130 + c] = (f16)loi[c * NPIX + y * HWD + x];
        }
        __syncthreads();
        #pragma unroll
        for (int it = 0; it < 8; ++it) {
            int j = it * 256 + tid;      // 2048 chunks of 8 f16
            int x = j >> 4, cc = (j & 15) * 8;
            f16x8 v;
            #pragma unroll
            for (int u = 0; u < 8; ++u) v[u] = t[x * 130 + cc + u];
            *(f16x8*)(loiT + (y * HWD + x) * HWD + cc) = v;
        }
    } else if (bid < 640) {
        const int b = bid - 128;         // 0..511
        const float* W = (b < 256) ? W1 : W2;
        f16* Wt = (b < 256) ? W1T : W2T;
        const int bb = b & 255;
        __shared__ f16 t[64 * 66];
        const int k0 = (bb >> 4) * 64;
        const int n0 = (bb & 15) * 64;
        #pragma unroll 4
        for (int it = 0; it < 16; ++it) {
            int i = it * 256 + tid;      // coalesced read over n
            int r = i >> 6, c = i & 63;
            t[c * 66 + r] = (f16)W[(size_t)(k0 + r) * NDIM + n0 + c];
        }
        __syncthreads();
        #pragma unroll
        for (int it = 0; it < 2; ++it) {
            int j = it * 256 + tid;
            int nr = j >> 3, kc = (j & 7) * 8;
            f16x8 v;
            #pragma unroll
            for (int u = 0; u < 8; ++u) v[u] = t[nr * 66 + kc + u];
            const int kk = k0 + kc;      // multiple of 8
            const int n = n0 + nr;
            const int slot = ((kk >> 3) & 3) ^ ((n >> 1) & 3);
            *(f16x8*)(Wt + ((size_t)(kk >> 5) * NDIM + n) * 32 + slot * 8) = v;
        }
    } else if (bid < 704) {
        const int p = (bid - 640) * 256 + tid;   // 64 blocks x 256 = 16384
        const int y = p >> 7, x = p & 127;
        const float c = jloc[p];
        float m = c;
        for (int dy = -1; dy <= 1; ++dy) {
            int yy = y + dy;
            if (yy < 0 || yy >= HWD) continue;
            for (int dx = -1; dx <= 1; ++dx) {
                int xx = x + dx;
                if (xx < 0 || xx >= HWD) continue;
                m = fmaxf(m, jloc[yy * HWD + xx]);
            }
        }
        if (c == m && c > 0.0f) {
            int pos = atomicAdd(count, 1);
            if (pos < MAXCAND) {
                unsigned int ub = __float_as_uint(c);
                cand[pos] = ((unsigned long long)ub << 32) |
                            (unsigned long long)(0xFFFFFFFFu - (unsigned int)p);
            }
        }
    } else {
        const int base = (bid - 704) * 1024 + tid * 4;   // 60 blocks cover 61440
        #pragma unroll
        for (int u = 0; u < 4; ++u)
            if (base + u < out_n) out[base + u] = 0.f;
    }
}

// ---------------------------------------------------------------------------
// Rank-select top-300, LDS-cached. Keys unique => ranks exact; matches
// jax.lax.top_k order (value desc, index asc).
// ---------------------------------------------------------------------------
__global__ __launch_bounds__(256) void rank_junc_kernel(
    const unsigned long long* __restrict__ cand, const int* __restrict__ count,
    const float* __restrict__ joff, float* __restrict__ juncs /* [300][2] */)
{
    __shared__ unsigned long long keys[MAXCAND];   // 32 KB
    const int n = min(*count, MAXCAND);
    const int t = blockIdx.x * 256 + threadIdx.x;  // 16 blocks = 4096 threads
    for (int i = threadIdx.x; i < n; i += 256)
        keys[i] = cand[i];
    __syncthreads();
    if (t >= n) return;
    const unsigned long long key = keys[t];
    int rank = 0;
    int j = 0;
    for (; j + 4 <= n; j += 4) {
        rank += (keys[j]     > key);
        rank += (keys[j + 1] > key);
        rank += (keys[j + 2] > key);
        rank += (keys[j + 3] > key);
    }
    for (; j < n; ++j) rank += (keys[j] > key);
    if (rank < TOPK_N) {
        unsigned int p = 0xFFFFFFFFu - (unsigned int)(key & 0xFFFFFFFFull);
        // x = idx%w + (sigmoid(joff0)-0.5) + 0.5 = idx%w + sigmoid(joff0)
        float sx = 1.0f / (1.0f + expf(-joff[p]));
        float sy = 1.0f / (1.0f + expf(-joff[NPIX + p]));
        juncs[2 * rank + 0] = (float)(p & 127) + sx;
        juncs[2 * rank + 1] = (float)(p >> 7) + sy;
    }
}

// ---------------------------------------------------------------------------
// Per-line sampling, deduplicated: lanes 0..31 compute the 4 tap offsets +
// weights of the 32 points once into LDS; channel loop (64 lanes, 2 ch each)
// reads them as wave-uniform broadcasts. 4 lines/block (wave per line).
// Output feats in the XOR-swizzled A operand layout.
// ---------------------------------------------------------------------------
__global__ __launch_bounds__(256) void sample_kernel(
    const f16* __restrict__ loiT, const float* __restrict__ juncs,
    const int* __restrict__ edge_idx, f16* __restrict__ feats)
{
    const int wv = threadIdx.x >> 6;
    const int l = blockIdx.x * 4 + wv;
    const int lane = threadIdx.x & 63;

    __shared__ int   soff[4][32][4];   // channel-base element offsets
    __shared__ float swt[4][32][4];    // bilinear weights

    if (lane < 32) {
        const int e0 = edge_idx[2 * l], e1 = edge_idx[2 * l + 1];
        const float ux = juncs[2 * e0], uy = juncs[2 * e0 + 1];
        const float vx = juncs[2 * e1], vy = juncs[2 * e1 + 1];
        const int j = lane;
        const float t = (float)j * (1.0f / 31.0f);
        const float px = ux * t + vx * (1.0f - t) - 0.5f;
        const float py = uy * t + vy * (1.0f - t) - 0.5f;
        float fx0 = fminf(fmaxf(floorf(px), 0.0f), 127.0f);
        float fy0 = fminf(fmaxf(floorf(py), 0.0f), 127.0f);
        float fx1 = fminf(fx0 + 1.0f, 127.0f);
        float fy1 = fminf(fy0 + 1.0f, 127.0f);
        int ix0 = (int)fx0, iy0 = (int)fy0, ix1 = (int)fx1, iy1 = (int)fy1;
        soff[wv][j][0] = (iy0 * HWD + ix0) * HWD;
        soff[wv][j][1] = (iy1 * HWD + ix0) * HWD;
        soff[wv][j][2] = (iy0 * HWD + ix1) * HWD;
        soff[wv][j][3] = (iy1 * HWD + ix1) * HWD;
        swt[wv][j][0] = (fy1 - py) * (fx1 - px);
        swt[wv][j][1] = (py - fy0) * (fx1 - px);
        swt[wv][j][2] = (fy1 - py) * (px - fx0);
        swt[wv][j][3] = (py - fy0) * (px - fx0);
    }
    __syncthreads();

    const int c2 = lane * 2;
    f16x8 o0, o1;
    #pragma unroll
    for (int p = 0; p < 8; ++p) {
        float m0 = -INFINITY, m1 = -INFINITY;
        #pragma unroll
        for (int jj = 0; jj < 4; ++jj) {
            const int j = p * 4 + jj;
            const int b00 = soff[wv][j][0], b10 = soff[wv][j][1];
            const int b01 = soff[wv][j][2], b11 = soff[wv][j][3];
            const float w00 = swt[wv][j][0], w10 = swt[wv][j][1];
            const float w01 = swt[wv][j][2], w11 = swt[wv][j][3];
            f16x2 v00 = *(const f16x2*)(loiT + b00 + c2);
            f16x2 v10 = *(const f16x2*)(loiT + b10 + c2);
            f16x2 v01 = *(const f16x2*)(loiT + b01 + c2);
            f16x2 v11 = *(const f16x2*)(loiT + b11 + c2);
            float s0 = (float)v00.x * w00 + (float)v10.x * w10 +
                       (float)v01.x * w01 + (float)v11.x * w11;
            float s1 = (float)v00.y * w00 + (float)v10.y * w10 +
                       (float)v01.y * w01 + (float)v11.y * w11;
            m0 = fmaxf(m0, s0);
            m1 = fmaxf(m1, s1);
        }
        o0[p] = (f16)m0;   // feature k = 16*lane + p
        o1[p] = (f16)m1;   // feature k = 16*lane + 8 + p
    }
    // A layout: chunk = lane>>1; o0 oct = 2*(lane&1), o1 oct = 2*(lane&1)+1;
    // slot = oct ^ ((l>>1)&3).
    const int rs = (l >> 1) & 3;
    const int oct0 = (lane & 1) * 2;
    f16* base = feats + ((size_t)(lane >> 1) * MPAD + l) * 32;
    *(f16x8*)(base + ((oct0 ^ rs) * 8)) = o0;
    *(f16x8*)(base + (((oct0 + 1) ^ rs) * 8)) = o1;
}

// ---------------------------------------------------------------------------
// GEMM: 160x256 tile, 256 threads, 2x2 waves (each 80 rows x 128 cols,
// acc[5][8]). 32 rounds of one BK=32 chunk. Ring of 3 round-buffers
// (26 KiB each: A 10 KiB + B 16 KiB), prefetch distance 2. Per round:
//   s_waitcnt vmcnt(7|6)  <- per-wave counted: forces THIS round's buffer
//                            (staged 2 rounds ago); next round's loads stay
//                            in flight. Last round drains vmcnt(0).
//   s_barrier             <- all waves' segs complete; reads of the buffer
//                            being overwritten finished one round ago
//   STAGE(c+2)            <- G2L into buffer (c+2)%3
//   ds_read af[5]/bf[8] (XOR-swizzled, conflict-free) + 40 MFMA
// 1D grid 504 = 63 tiles x 8 XCDs, XCD-chunked: tile = (id&7)*63 + (id>>3),
// mblk = tile>>2 (mblk-major within XCD) -> A-panel's 4 consumer tiles all
// in one XCD (1 HBM fetch + 3 L2 hits); B slices per XCD = 2 MB resident.
// LDS 78 KiB -> 2 blocks/CU (cross-block interleave hides round overhead).
// head=0: C = relu(A@Bt^T + bias), stored in swizzled A layout fp16.
// head=1: v = relu(A@Bt^T + bias); out[m][j] += v . W3  (atomicAdd, + b3 once)
// ---------------------------------------------------------------------------
__global__ __launch_bounds__(256, 2) void gemm_bias_relu_kernel(
    const f16* __restrict__ A, const f16* __restrict__ Bt,
    const float* __restrict__ bias, f16* __restrict__ C,
    const float* __restrict__ W3, const float* __restrict__ b3,
    float* __restrict__ out, int K, int head)
{
    extern __shared__ f16 lds[];                 // 3 * 13312 f16 = 78 KiB
    const int tid = threadIdx.x;
    const int wave = tid >> 6, lane = tid & 63;
    const int wm = wave >> 1, wn = wave & 1;

    // XCD-chunked bijective tile mapping (504 = 8 XCDs x 63 tiles).
    const int id = blockIdx.x;
    const int tile = (id & 7) * 63 + (id >> 3);
    const int mblk = tile >> 2, nblk = tile & 3;
    const int m0 = mblk * 160;
    const int n0 = nblk * 256;

    const int col16 = lane & 15;
    const int quad = lane >> 4;
    const int swz = (quad ^ ((col16 >> 1) & 3)) * 8;   // lane-const slot offset

    f32x4 acc[5][8];
    #pragma unroll
    for (int mi = 0; mi < 5; ++mi)
        #pragma unroll
        for (int ni = 0; ni < 8; ++ni)
            acc[mi][ni] = (f32x4){0.f, 0.f, 0.f, 0.f};

    const size_t strideA = (size_t)MPAD * 32;    // f16 per k-chunk
    const size_t strideB = (size_t)NDIM * 32;
    // A chunk: contiguous 5120 f16 (10 segs of 1 KiB); wave w stages segs
    // {w, w+4} and (w<2) seg {8+w}. B chunk: 8192 f16; wave w stages 4 segs
    // {4w..4w+3}. lane deposits seg_base + lane*16B. Global == LDS order.
    const f16* gA = A + (size_t)m0 * 32 + wave * 512 + lane * 8;
    const f16* gB = Bt + (size_t)n0 * 32 + wave * 2048 + lane * 8;
    const int sAo = wave * 512;                  // + lane*16B implicit
    const int sBo = wave * 2048;

#define STAGE(CN) do { \
        f16* lb_ = lds + ((CN) % 3) * 13312; \
        const f16* ga_ = gA + (size_t)(CN) * strideA; \
        G2L(ga_,        lb_ + sAo); \
        G2L(ga_ + 2048, lb_ + sAo + 2048); \
        if (wave < 2) G2L(ga_ + 4096, lb_ + sAo + 4096); \
        const f16* gb_ = gB + (size_t)(CN) * strideB; \
        G2L(gb_,        lb_ + 5120 + sBo); \
        G2L(gb_ + 512,  lb_ + 5120 + sBo + 512); \
        G2L(gb_ + 1024, lb_ + 5120 + sBo + 1024); \
        G2L(gb_ + 1536, lb_ + 5120 + sBo + 1536); \
    } while (0)

    // Prologue: order pinned so each wave's oldest G2L batch is STAGE(0).
    STAGE(0);
    asm volatile("" ::: "memory");
    STAGE(1);
    asm volatile("" ::: "memory");

    const int NC = K >> 5;                       // 32 chunks
    for (int c = 0; c < NC; ++c) {
        if (c + 1 < NC) {
            if (wave < 2) asm volatile("s_waitcnt vmcnt(7)" ::: "memory");
            else          asm volatile("s_waitcnt vmcnt(6)" ::: "memory");
        } else {
            asm volatile("s_waitcnt vmcnt(0)" ::: "memory");
        }
        __builtin_amdgcn_s_barrier();
        if (c + 2 < NC) STAGE(c + 2);
        asm volatile("" ::: "memory");

        const f16* buf = lds + (c % 3) * 13312;
        const f16* pA = buf + (wm * 80 + col16) * 32 + swz;
        const f16* pB = buf + 5120 + (wn * 128 + col16) * 32 + swz;
        f16x8 af[5], bf[8];
        #pragma unroll
        for (int i = 0; i < 5; ++i)
            af[i] = *(const f16x8*)(pA + i * 512);
        #pragma unroll
        for (int i = 0; i < 8; ++i)
            bf[i] = *(const f16x8*)(pB + i * 512);
        #pragma unroll
        for (int mi = 0; mi < 5; ++mi)
            #pragma unroll
            for (int ni = 0; ni < 8; ++ni)
                acc[mi][ni] = __builtin_amdgcn_mfma_f32_16x16x32_f16(
                    af[mi], bf[ni], acc[mi][ni], 0, 0, 0);
    }
#undef STAGE

    if (!head) {
        #pragma unroll
        for (int ni = 0; ni < 8; ++ni) {
            const int n = n0 + wn * 128 + ni * 16 + col16;
            const float b = bias[n];
            const size_t rb = (size_t)(n >> 5) * MPAD;
            const int noct = (n >> 3) & 3, ne = n & 7;
            #pragma unroll
            for (int mi = 0; mi < 5; ++mi) {
                #pragma unroll
                for (int r = 0; r < 4; ++r) {
                    const int m = m0 + wm * 80 + mi * 16 + quad * 4 + r;
                    float v = fmaxf(acc[mi][ni][r] + b, 0.f);
                    C[(rb + m) * 32 + ((noct ^ ((m >> 1) & 3)) * 8) + ne] = (f16)v;
                }
            }
        }
    } else {
        float bb[8], w3c[8][3];
        #pragma unroll
        for (int ni = 0; ni < 8; ++ni) {
            const int n = n0 + wn * 128 + ni * 16 + col16;
            bb[ni] = bias[n];
            #pragma unroll
            for (int jj = 0; jj < 3; ++jj) w3c[ni][jj] = W3[n * 3 + jj];
        }
        const bool addb3 = (nblk == 0 && wn == 0);
        #pragma unroll
        for (int mi = 0; mi < 5; ++mi) {
            #pragma unroll
            for (int r = 0; r < 4; ++r) {
                float s0 = 0.f, s1 = 0.f, s2 = 0.f;
                #pragma unroll
                for (int ni = 0; ni < 8; ++ni) {
                    float v = fmaxf(acc[mi][ni][r] + bb[ni], 0.f);
                    s0 += v * w3c[ni][0];
                    s1 += v * w3c[ni][1];
                    s2 += v * w3c[ni][2];
                }
                #pragma unroll
                for (int mask = 1; mask <= 8; mask <<= 1) {
                    s0 += __shfl_xor(s0, mask);
                    s1 += __shfl_xor(s1, mask);
                    s2 += __shfl_xor(s2, mask);
                }
                if (col16 == 0) {
                    const int m = m0 + wm * 80 + mi * 16 + quad * 4 + r;
                    if (m < NLINES) {
                        atomicAdd(&out[m * 3 + 0], s0 + (addb3 ? b3[0] : 0.f));
                        atomicAdd(&out[m * 3 + 1], s1 + (addb3 ? b3[1] : 0.f));
                        atomicAdd(&out[m * 3 + 2], s2 + (addb3 ? b3[2] : 0.f));
                    }
                }
            }
        }
    }
}

// ---------------------------------------------------------------------------
extern "C" void kernel_launch(void* const* d_in, const int* in_sizes, int n_in,
                              void* d_out, int out_size, void* d_ws, size_t ws_size,
                              hipStream_t stream)
{
    const float* jloc = (const float*)d_in[0];
    const float* joff = (const float*)d_in[1];
    const float* loi  = (const float*)d_in[2];
    const int*   eidx = (const int*)d_in[3];
    const float* W1   = (const float*)d_in[4];
    const float* b1   = (const float*)d_in[5];
    const float* W2   = (const float*)d_in[6];
    const float* b2   = (const float*)d_in[7];
    const float* W3   = (const float*)d_in[8];
    const float* b3   = (const float*)d_in[9];
    float* out = (float*)d_out;

    char* ws = (char*)d_ws;
    f16*   loiT  = (f16*)(ws);                            // 4 MB
    f16*   W1T   = (f16*)(ws + ((size_t)4 << 20));        // 2 MB
    f16*   W2T   = (f16*)(ws + ((size_t)6 << 20));        // 2 MB
    float* juncs = (float*)(ws + ((size_t)8 << 20));      // 2.4 KB
    int*   count = (int*)(ws + ((size_t)8 << 20) + 4096);
    unsigned long long* cand =
        (unsigned long long*)(ws + ((size_t)8 << 20) + 8192);  // 32 KB
    f16*   feats = (f16*)(ws + ((size_t)9 << 20));        // 41.3 MB (tiled MPADx1024)
    f16*   h1    = (f16*)(ws + ((size_t)52 << 20));       // 41.3 MB (tiled)

    static int attr_done = 0;
    if (!attr_done) {
        (void)hipFuncSetAttribute(
            reinterpret_cast<const void*>(&gemm_bias_relu_kernel),
            hipFuncAttributeMaxDynamicSharedMemorySize, 79872);
        attr_done = 1;
    }

    hipMemsetAsync(count, 0, sizeof(int), stream);
    preproc_kernel<<<dim3(764), dim3(256), 0, stream>>>(
        loi, loiT, W1, W1T, W2, W2T, jloc, cand, count, out, out_size);
    rank_junc_kernel<<<dim3(MAXCAND / 256), dim3(256), 0, stream>>>(
        cand, count, joff, juncs);
    sample_kernel<<<dim3(NLINES / 4), dim3(256), 0, stream>>>(loiT, juncs, eidx, feats);
    gemm_bias_relu_kernel<<<dim3(504), dim3(256), 79872, stream>>>(
        feats, W1T, b1, h1, nullptr, nullptr, nullptr, KDIM, 0);
    gemm_bias_relu_kernel<<<dim3(504), dim3(256), 79872, stream>>>(
        h1, W2T, b2, nullptr, W3, b3, out, KDIM, 1);
}